// Round 1
// 294.845 us; speedup vs baseline: 1.0036x; 1.0036x over previous
//
#include <hip/hip_runtime.h>

#define N_NODES 100000
#define N_EDGES 1600000
#define FIN 256
#define FOUT 128
#define LRELU_ALPHA 0.2f

#define NBUCKET 391          // dst>>8, 256 dsts per bucket
#define PBLOCKS 256
#define PCHUNK  (N_EDGES / PBLOCKS)   // 6250
#define BCAP    5120         // slab capacity: mean 4096, sigma 64 -> +16 sigma

using bf16x8 = __attribute__((ext_vector_type(8))) short;
using f32x4  = __attribute__((ext_vector_type(4))) float;
using v2f    = __attribute__((ext_vector_type(2))) float;

static __device__ __forceinline__ unsigned short f2bf(float f) {
    union { float f; unsigned u; } v; v.f = f;
    unsigned r = (v.u + 0x7FFF + ((v.u >> 16) & 1)) >> 16;  // RNE
    return (unsigned short)r;
}

static __device__ __forceinline__ bf16x8 cvt8(float4 a, float4 b) {
    union { bf16x8 v; unsigned short u[8]; } r;
    r.u[0] = f2bf(a.x); r.u[1] = f2bf(a.y); r.u[2] = f2bf(a.z); r.u[3] = f2bf(a.w);
    r.u[4] = f2bf(b.x); r.u[5] = f2bf(b.y); r.u[6] = f2bf(b.z); r.u[7] = f2bf(b.w);
    return r.v;
}

static __device__ __forceinline__ void gld_lds16(const unsigned short* g, unsigned short* l) {
    __builtin_amdgcn_global_load_lds(
        (const __attribute__((address_space(1))) unsigned int*)g,
        (__attribute__((address_space(3))) unsigned int*)l, 16, 0, 0);
}

// unpack two bf16 packed in a u32 -> float2 (elem0 = low half = even col)
static __device__ __forceinline__ v2f up2(unsigned u) {
    v2f r;
    r.x = __int_as_float((int)(u << 16));
    r.y = __int_as_float((int)(u & 0xFFFF0000u));
    return r;
}

// ---------------------------------------------------------------------------
// K0: wt_sw = bf16(W^T) with bank-swizzle; block 0 also zeroes bcnt.
// ---------------------------------------------------------------------------
__global__ void k_wt(const float* __restrict__ w, unsigned short* __restrict__ wt_sw,
                     int* __restrict__ bcnt)
{
    if (blockIdx.x == 0)
        for (int z = threadIdx.x; z < NBUCKET; z += 256) bcnt[z] = 0;
    int i = blockIdx.x * blockDim.x + threadIdx.x;   // 32768
    if (i >= FIN * FOUT) return;
    int k = i >> 7, n = i & 127;
    wt_sw[n * FIN + (((k >> 3) ^ (n & 7)) << 3) + (k & 7)] = f2bf(w[k * FOUT + n]);
}

// ---------------------------------------------------------------------------
// K1: h_bf16 = bf16(x @ W) + fused scores (unchanged from R4).
// ---------------------------------------------------------------------------
__global__ __launch_bounds__(256, 2) void k_gemm3(
    const float* __restrict__ x, const unsigned short* __restrict__ wt_sw,
    const float* __restrict__ a_l, const float* __restrict__ a_r,
    unsigned short* __restrict__ hb, float* __restrict__ score_l,
    float* __restrict__ score_r)
{
    __shared__ unsigned short wlds[FOUT * FIN];      // 64 KB

    const int tid  = threadIdx.x;
    const int lane = tid & 63;
    const int wid  = tid >> 6;
    const int m    = lane & 15;
    const int q    = lane >> 4;

    {
        const unsigned short* g = wt_sw + wid * 8192;
        unsigned short*       l = wlds  + wid * 8192;
#pragma unroll
        for (int i = 0; i < 16; ++i)
            gld_lds16(g + i * 512 + lane * 8, l + i * 512);
    }

    const int row0 = blockIdx.x * 128 + wid * 32;
    int r0 = row0 + m;       if (r0 > N_NODES - 1) r0 = N_NODES - 1;
    int r1 = row0 + 16 + m;  if (r1 > N_NODES - 1) r1 = N_NODES - 1;
    const float* xp0 = x + (long)r0 * FIN + q * 8;
    const float* xp1 = x + (long)r1 * FIN + q * 8;

    float4 xb[2][2][2];
    xb[0][0][0] = *(const float4*)(xp0);        xb[0][0][1] = *(const float4*)(xp0 + 4);
    xb[0][1][0] = *(const float4*)(xp1);        xb[0][1][1] = *(const float4*)(xp1 + 4);
    xb[1][0][0] = *(const float4*)(xp0 + 32);   xb[1][0][1] = *(const float4*)(xp0 + 36);
    xb[1][1][0] = *(const float4*)(xp1 + 32);   xb[1][1][1] = *(const float4*)(xp1 + 36);

    f32x4 acc[2][8];
#pragma unroll
    for (int mt = 0; mt < 2; ++mt)
#pragma unroll
        for (int nt = 0; nt < 8; ++nt) acc[mt][nt] = (f32x4){0.f, 0.f, 0.f, 0.f};

    __syncthreads();

    const int xr = m & 7;

    bf16x8 bfr[2][8];
#pragma unroll
    for (int nt = 0; nt < 8; ++nt)
        bfr[0][nt] = *(const bf16x8*)&wlds[(nt * 16 + m) * FIN + ((q ^ xr) << 3)];

#pragma unroll
    for (int s = 0; s < 8; ++s) {
        const int p = s & 1;
        bf16x8 a0 = cvt8(xb[p][0][0], xb[p][0][1]);
        bf16x8 a1 = cvt8(xb[p][1][0], xb[p][1][1]);
        if (s + 2 < 8) {
            xb[p][0][0] = *(const float4*)(xp0 + (s + 2) * 32);
            xb[p][0][1] = *(const float4*)(xp0 + (s + 2) * 32 + 4);
            xb[p][1][0] = *(const float4*)(xp1 + (s + 2) * 32);
            xb[p][1][1] = *(const float4*)(xp1 + (s + 2) * 32 + 4);
        }
        if (s + 1 < 8) {
#pragma unroll
            for (int nt = 0; nt < 8; ++nt)
                bfr[1 - p][nt] = *(const bf16x8*)
                    &wlds[(nt * 16 + m) * FIN + ((((s + 1) * 4 + q) ^ xr) << 3)];
        }
#pragma unroll
        for (int nt = 0; nt < 8; ++nt) {
            acc[0][nt] = __builtin_amdgcn_mfma_f32_16x16x32_bf16(a0, bfr[p][nt], acc[0][nt], 0, 0, 0);
            acc[1][nt] = __builtin_amdgcn_mfma_f32_16x16x32_bf16(a1, bfr[p][nt], acc[1][nt], 0, 0, 0);
        }
    }

    float al[8], ar[8];
#pragma unroll
    for (int nt = 0; nt < 8; ++nt) { al[nt] = a_l[nt * 16 + m]; ar[nt] = a_r[nt * 16 + m]; }

#pragma unroll
    for (int mt = 0; mt < 2; ++mt) {
#pragma unroll
        for (int r = 0; r < 4; ++r) {
            const int node = row0 + mt * 16 + q * 4 + r;
            const bool ok = node < N_NODES;
            float sl = 0.f, sr = 0.f;
#pragma unroll
            for (int nt = 0; nt < 8; ++nt) {
                float v = acc[mt][nt][r];
                if (ok) hb[node * FOUT + nt * 16 + m] = f2bf(v);
                sl = fmaf(v, al[nt], sl);
                sr = fmaf(v, ar[nt], sr);
            }
#pragma unroll
            for (int msk = 1; msk < 16; msk <<= 1) {
                sl += __shfl_xor(sl, msk, 64);
                sr += __shfl_xor(sr, msk, 64);
            }
            if (ok && m == 0) { score_l[node] = sl; score_r[node] = sr; }
        }
    }
}

// ---------------------------------------------------------------------------
// K2: partition edges into per-bucket SLABS (no global scan needed).
// Per-block space reserved with one atomicAdd per bucket.
// rec = (dst&255)<<17 | src
// ---------------------------------------------------------------------------
__global__ __launch_bounds__(512) void k_part(const int* __restrict__ ei,
                                              int* __restrict__ bcnt,
                                              unsigned* __restrict__ part)
{
    __shared__ unsigned staging[PCHUNK];
    __shared__ unsigned short bkt[PCHUNK];
    __shared__ int cnt[512];
    __shared__ int loc[512];
    __shared__ int gbase[NBUCKET];   // slab-local base for this block

    const int tid = threadIdx.x;
    const int e0  = blockIdx.x * PCHUNK;

    cnt[tid] = 0;
    __syncthreads();

    for (int i = tid; i < PCHUNK; i += 512)
        atomicAdd(&cnt[ei[e0 + i] >> 8], 1);
    __syncthreads();

    int v = cnt[tid];
    loc[tid] = v;
    __syncthreads();
    for (int off = 1; off < 512; off <<= 1) {
        int t = (tid >= off) ? loc[tid - off] : 0;
        __syncthreads();
        loc[tid] += t;
        __syncthreads();
    }
    int excl = loc[tid] - v;
    if (tid < NBUCKET && v > 0) gbase[tid] = atomicAdd(&bcnt[tid], v);
    loc[tid] = excl;
    cnt[tid] = excl;
    __syncthreads();

    for (int i = tid; i < PCHUNK; i += 512) {
        int dst = ei[e0 + i];
        int src = ei[N_EDGES + e0 + i];
        int b = dst >> 8;
        unsigned rec = ((unsigned)(dst & 255) << 17) | (unsigned)src;
        int p = atomicAdd(&cnt[b], 1);
        staging[p] = rec;
        bkt[p] = (unsigned short)b;
    }
    __syncthreads();

    for (int i = tid; i < PCHUNK; i += 512) {
        int b = bkt[i];
        int off = gbase[b] + (i - loc[b]);
        if (off < BCAP) part[b * BCAP + off] = staging[i];
    }
}

// ---------------------------------------------------------------------------
// K3: per-bucket counting sort by dstLow -> sorted src slab + rowbeg/rowend.
// ---------------------------------------------------------------------------
__global__ __launch_bounds__(512) void k_bucket(const unsigned* __restrict__ part,
                                                const int* __restrict__ bcnt,
                                                int* __restrict__ rowbeg,
                                                int* __restrict__ rowend,
                                                unsigned* __restrict__ csrs)
{
    __shared__ unsigned rin[BCAP];
    __shared__ unsigned rs[BCAP];
    __shared__ int hist[256];
    __shared__ int tmp[512];

    const int b   = blockIdx.x;
    const int tid = threadIdx.x;
    const int beg = b * BCAP;
    int cnt = bcnt[b];
    if (cnt > BCAP) cnt = BCAP;
    const int d0 = b << 8;

    if (tid < 256) hist[tid] = 0;
    __syncthreads();

    for (int i = tid; i < cnt; i += 512) {
        unsigned rec = part[beg + i];
        rin[i] = rec;
        atomicAdd(&hist[rec >> 17], 1);
    }
    __syncthreads();

    int v = (tid < 256) ? hist[tid] : 0;
    tmp[tid] = v;
    __syncthreads();
    for (int off = 1; off < 512; off <<= 1) {
        int t = (tid >= off) ? tmp[tid - off] : 0;
        __syncthreads();
        tmp[tid] += t;
        __syncthreads();
    }
    if (tid < 256) {
        int excl = tmp[tid] - v;
        hist[tid] = excl;          // cursor
        int d = d0 + tid;
        if (d < N_NODES) { rowbeg[d] = beg + excl; rowend[d] = beg + excl + v; }
    }
    __syncthreads();

    for (int i = tid; i < cnt; i += 512) {
        unsigned rec = rin[i];
        int p = atomicAdd(&hist[rec >> 17], 1);
        rs[p] = rec;
    }
    __syncthreads();

    for (int i = tid; i < cnt; i += 512)
        csrs[beg + i] = rs[i];
}

// ---------------------------------------------------------------------------
// K4: fused softmax-SpMM + bias + sigmoid-gate.
// NEW: one WAVE = one node. The wave's four 16-lane groups each take one
// edge per iteration (edges beg+4i+g) -> no cross-node divergence (loop
// bound is wave-uniform), and a 2-deep software pipeline keeps 8 edges'
// gathers in flight: csrs prefetched 2 iters ahead, score_r/hb row issued
// 1 iter ahead. Final shfl_xor(16/32) butterfly folds group partials.
// ---------------------------------------------------------------------------
__global__ __launch_bounds__(256) void k_spmm_gate(
    const int* __restrict__ rowbeg, const int* __restrict__ rowend,
    const unsigned* __restrict__ csrs,
    const unsigned short* __restrict__ hb,
    const float* __restrict__ score_l, const float* __restrict__ score_r,
    const float* __restrict__ bias, const float* __restrict__ fc,
    const float* __restrict__ bf, float* __restrict__ out)
{
    const int lane = threadIdx.x & 63;
    const int g    = lane >> 4;                  // edge subgroup 0..3
    const int t    = lane & 15;                  // col group: t*8 .. t*8+7
    const int node = blockIdx.x * 4 + (threadIdx.x >> 6);
    if (node >= N_NODES) return;

    const int beg = rowbeg[node], end = rowend[node];
    const int deg = end - beg;
    const float sl = score_l[node];

    v2f a0 = {0.f, 0.f}, a1 = {0.f, 0.f}, a2 = {0.f, 0.f}, a3 = {0.f, 0.f};
    float denom = 0.f;

    if (deg > 0) {
        const int nit  = (deg + 3) >> 2;         // wave-uniform
        const int last = end - 1;

        // iteration i handles edge j = beg + 4*i + g (per group g)
        int j = beg + g;                         // current edge index
        int jc = j <= last ? j : last;
        unsigned recA = csrs[jc];                // rec for iter 0 (arrived)
        unsigned recB = recA;                    // rec for iter 1
        if (nit > 1) {
            int j1 = j + 4;
            int jc1 = j1 <= last ? j1 : last;
            recB = csrs[jc1];
        }
        // issue gathers for iter 0
        int   sA   = recA & 0x1FFFF;
        float srA  = score_r[sA];
        uint4 rowA = *(const uint4*)&hb[sA * FOUT + t * 8];
        bool  vA   = j < end;

        for (int i = 0; i < nit; ++i) {
            // prefetch rec for iter i+2 (address-independent of loop body)
            unsigned recC = recB;
            if (i + 2 < nit) {
                int j2 = j + 8;
                int jc2 = j2 <= last ? j2 : last;
                recC = csrs[jc2];
            }
            // issue gathers for iter i+1 from recB (arrived one iter ago)
            float srB = 0.f;
            uint4 rowB = {0u, 0u, 0u, 0u};
            bool  vB = false;
            if (i + 1 < nit) {
                int sB = recB & 0x1FFFF;
                srB  = score_r[sB];
                rowB = *(const uint4*)&hb[sB * FOUT + t * 8];
                vB   = (j + 4) < end;
            }
            // consume iter i (loads issued one iteration ago)
            float e = sl + srA;
            e = e > 0.f ? e : LRELU_ALPHA * e;
            float w = vA ? __expf(e) : 0.f;
            denom += w;
            v2f w2 = {w, w};
            a0 += w2 * up2(rowA.x);  a1 += w2 * up2(rowA.y);
            a2 += w2 * up2(rowA.z);  a3 += w2 * up2(rowA.w);
            // rotate pipeline
            recB = recC; srA = srB; rowA = rowB; vA = vB;
            j += 4;
        }
    }

    // fold the 4 groups' partial accumulators + denominator (lanes differ
    // only in bits 4..5 for a given column slot t)
    float accf[8] = {a0.x, a0.y, a1.x, a1.y, a2.x, a2.y, a3.x, a3.y};
#pragma unroll
    for (int k = 0; k < 8; ++k) {
        accf[k] += __shfl_xor(accf[k], 16, 64);
        accf[k] += __shfl_xor(accf[k], 32, 64);
    }
    denom += __shfl_xor(denom, 16, 64);
    denom += __shfl_xor(denom, 32, 64);

    const float inv = 1.0f / (denom + 1e-16f);

    float vx[8];
    float gp = 0.f;
#pragma unroll
    for (int i = 0; i < 8; ++i) {
        vx[i] = fmaf(accf[i], inv, bias[t * 8 + i]);
        gp = fmaf(vx[i], fc[t * 8 + i], gp);
    }
    // reduce gate partial across the 16 column lanes (bits 0..3); groups are
    // already identical after the accf butterfly
#pragma unroll
    for (int msk = 1; msk < 16; msk <<= 1) gp += __shfl_xor(gp, msk, 64);
    const float gate = 1.0f / (1.0f + __expf(-(gp + bf[0])));

    float4 o;
    float* ov = &o.x;
    if (g == 0) {
#pragma unroll
        for (int i = 0; i < 4; ++i) {
            float v2 = vx[i];
            ov[i] = (v2 < 0.f ? 0.f : v2) + gate * (v2 > 0.f ? 0.f : v2);
        }
        *(float4*)&out[node * FOUT + t * 8] = o;
    } else if (g == 1) {
#pragma unroll
        for (int i = 0; i < 4; ++i) {
            float v2 = vx[4 + i];
            ov[i] = (v2 < 0.f ? 0.f : v2) + gate * (v2 > 0.f ? 0.f : v2);
        }
        *(float4*)&out[node * FOUT + t * 8 + 4] = o;
    }
}

// ---------------------------------------------------------------------------
extern "C" void kernel_launch(void* const* d_in, const int* in_sizes, int n_in,
                              void* d_out, int out_size, void* d_ws, size_t ws_size,
                              hipStream_t stream)
{
    const float* x      = (const float*)d_in[0];
    const int*   ei     = (const int*)d_in[1];
    const float* weight = (const float*)d_in[3];
    const float* bias   = (const float*)d_in[4];
    const float* a_l    = (const float*)d_in[5];
    const float* a_r    = (const float*)d_in[6];
    const float* fc     = (const float*)d_in[7];
    const float* bf     = (const float*)d_in[8];
    float* out = (float*)d_out;

    char* ws = (char*)d_ws;
    unsigned short* hb      = (unsigned short*)(ws);            // 25,600,000
    unsigned short* wt_sw   = (unsigned short*)(ws + 25600000); // 65,536
    float*          score_l = (float*)(ws + 25665536);          // 400,000
    float*          score_r = (float*)(ws + 26065536);          // 400,000
    int*            bcnt    = (int*)  (ws + 26465536);          // 2,048
    int*            rowbeg  = (int*)  (ws + 26467584);          // 400,000
    int*            rowend  = (int*)  (ws + 26867584);          // 400,000
    unsigned*       part    = (unsigned*)(ws + 27267584);       // 391*5120*4 = 8,007,680
    unsigned*       csrs    = (unsigned*)(ws + 35275264);       // 8,007,680
    // total ~43.3 MB

    k_wt<<<(FIN * FOUT + 255) / 256, 256, 0, stream>>>(weight, wt_sw, bcnt);

    k_gemm3<<<(N_NODES + 127) / 128, 256, 0, stream>>>(
        x, wt_sw, a_l, a_r, hb, score_l, score_r);

    k_part<<<PBLOCKS, 512, 0, stream>>>(ei, bcnt, part);
    k_bucket<<<NBUCKET, 512, 0, stream>>>(part, bcnt, rowbeg, rowend, csrs);

    k_spmm_gate<<<(N_NODES + 3) / 4, 256, 0, stream>>>(
        rowbeg, rowend, csrs, hb, score_l, score_r, bias, fc, bf, out);
}

// Round 2
// 292.953 us; speedup vs baseline: 1.0101x; 1.0065x over previous
//
#include <hip/hip_runtime.h>

#define N_NODES 100000
#define N_EDGES 1600000
#define FIN 256
#define FOUT 128
#define LRELU_ALPHA 0.2f

#define NBUCKET 391          // dst>>8, 256 dsts per bucket
#define PBLOCKS 256
#define PCHUNK  (N_EDGES / PBLOCKS)   // 6250
#define BCAP    5120         // slab capacity: mean 4096, sigma 64 -> +16 sigma

using bf16x8 = __attribute__((ext_vector_type(8))) short;
using f32x4  = __attribute__((ext_vector_type(4))) float;

static __device__ __forceinline__ unsigned short f2bf(float f) {
    union { float f; unsigned u; } v; v.f = f;
    unsigned r = (v.u + 0x7FFF + ((v.u >> 16) & 1)) >> 16;  // RNE
    return (unsigned short)r;
}

static __device__ __forceinline__ bf16x8 cvt8(float4 a, float4 b) {
    union { bf16x8 v; unsigned short u[8]; } r;
    r.u[0] = f2bf(a.x); r.u[1] = f2bf(a.y); r.u[2] = f2bf(a.z); r.u[3] = f2bf(a.w);
    r.u[4] = f2bf(b.x); r.u[5] = f2bf(b.y); r.u[6] = f2bf(b.z); r.u[7] = f2bf(b.w);
    return r.v;
}

static __device__ __forceinline__ void gld_lds16(const unsigned short* g, unsigned short* l) {
    __builtin_amdgcn_global_load_lds(
        (const __attribute__((address_space(1))) unsigned int*)g,
        (__attribute__((address_space(3))) unsigned int*)l, 16, 0, 0);
}

// h row is fp16; accumulate 8 cols with v_fma_mix_f32 (fma(fpext(f16),f32,f32))
static __device__ __forceinline__ void acc8(float* acc, uint4 r, float w) {
    union { uint4 u; _Float16 h[8]; } c; c.u = r;
#pragma unroll
    for (int k = 0; k < 8; ++k)
        acc[k] = fmaf((float)c.h[k], w, acc[k]);
}

// w = exp(leaky_relu(sl+sr))
static __device__ __forceinline__ float edgew(float sl, float sr) {
    float e = sl + sr;
    return __expf(fmaf(fminf(e, 0.f), LRELU_ALPHA, fmaxf(e, 0.f)));
}

// ---------------------------------------------------------------------------
// K0: wt_sw = bf16(W^T) with bank-swizzle; block 0 also zeroes bcnt.
// ---------------------------------------------------------------------------
__global__ void k_wt(const float* __restrict__ w, unsigned short* __restrict__ wt_sw,
                     int* __restrict__ bcnt)
{
    if (blockIdx.x == 0)
        for (int z = threadIdx.x; z < NBUCKET; z += 256) bcnt[z] = 0;
    int i = blockIdx.x * blockDim.x + threadIdx.x;   // 32768
    if (i >= FIN * FOUT) return;
    int k = i >> 7, n = i & 127;
    wt_sw[n * FIN + (((k >> 3) ^ (n & 7)) << 3) + (k & 7)] = f2bf(w[k * FOUT + n]);
}

// ---------------------------------------------------------------------------
// K1: h_f16 = fp16(x @ W) + fused scores. (h now stored as fp16 for the
// v_fma_mix_f32 accumulate path in K4; MFMA inputs stay bf16.)
// ---------------------------------------------------------------------------
__global__ __launch_bounds__(256, 2) void k_gemm3(
    const float* __restrict__ x, const unsigned short* __restrict__ wt_sw,
    const float* __restrict__ a_l, const float* __restrict__ a_r,
    unsigned short* __restrict__ hb, float* __restrict__ score_l,
    float* __restrict__ score_r)
{
    __shared__ unsigned short wlds[FOUT * FIN];      // 64 KB

    const int tid  = threadIdx.x;
    const int lane = tid & 63;
    const int wid  = tid >> 6;
    const int m    = lane & 15;
    const int q    = lane >> 4;

    {
        const unsigned short* g = wt_sw + wid * 8192;
        unsigned short*       l = wlds  + wid * 8192;
#pragma unroll
        for (int i = 0; i < 16; ++i)
            gld_lds16(g + i * 512 + lane * 8, l + i * 512);
    }

    const int row0 = blockIdx.x * 128 + wid * 32;
    int r0 = row0 + m;       if (r0 > N_NODES - 1) r0 = N_NODES - 1;
    int r1 = row0 + 16 + m;  if (r1 > N_NODES - 1) r1 = N_NODES - 1;
    const float* xp0 = x + (long)r0 * FIN + q * 8;
    const float* xp1 = x + (long)r1 * FIN + q * 8;

    float4 xb[2][2][2];
    xb[0][0][0] = *(const float4*)(xp0);        xb[0][0][1] = *(const float4*)(xp0 + 4);
    xb[0][1][0] = *(const float4*)(xp1);        xb[0][1][1] = *(const float4*)(xp1 + 4);
    xb[1][0][0] = *(const float4*)(xp0 + 32);   xb[1][0][1] = *(const float4*)(xp0 + 36);
    xb[1][1][0] = *(const float4*)(xp1 + 32);   xb[1][1][1] = *(const float4*)(xp1 + 36);

    f32x4 acc[2][8];
#pragma unroll
    for (int mt = 0; mt < 2; ++mt)
#pragma unroll
        for (int nt = 0; nt < 8; ++nt) acc[mt][nt] = (f32x4){0.f, 0.f, 0.f, 0.f};

    __syncthreads();

    const int xr = m & 7;

    bf16x8 bfr[2][8];
#pragma unroll
    for (int nt = 0; nt < 8; ++nt)
        bfr[0][nt] = *(const bf16x8*)&wlds[(nt * 16 + m) * FIN + ((q ^ xr) << 3)];

#pragma unroll
    for (int s = 0; s < 8; ++s) {
        const int p = s & 1;
        bf16x8 a0 = cvt8(xb[p][0][0], xb[p][0][1]);
        bf16x8 a1 = cvt8(xb[p][1][0], xb[p][1][1]);
        if (s + 2 < 8) {
            xb[p][0][0] = *(const float4*)(xp0 + (s + 2) * 32);
            xb[p][0][1] = *(const float4*)(xp0 + (s + 2) * 32 + 4);
            xb[p][1][0] = *(const float4*)(xp1 + (s + 2) * 32);
            xb[p][1][1] = *(const float4*)(xp1 + (s + 2) * 32 + 4);
        }
        if (s + 1 < 8) {
#pragma unroll
            for (int nt = 0; nt < 8; ++nt)
                bfr[1 - p][nt] = *(const bf16x8*)
                    &wlds[(nt * 16 + m) * FIN + ((((s + 1) * 4 + q) ^ xr) << 3)];
        }
#pragma unroll
        for (int nt = 0; nt < 8; ++nt) {
            acc[0][nt] = __builtin_amdgcn_mfma_f32_16x16x32_bf16(a0, bfr[p][nt], acc[0][nt], 0, 0, 0);
            acc[1][nt] = __builtin_amdgcn_mfma_f32_16x16x32_bf16(a1, bfr[p][nt], acc[1][nt], 0, 0, 0);
        }
    }

    float al[8], ar[8];
#pragma unroll
    for (int nt = 0; nt < 8; ++nt) { al[nt] = a_l[nt * 16 + m]; ar[nt] = a_r[nt * 16 + m]; }

    _Float16* hh = (_Float16*)hb;

#pragma unroll
    for (int mt = 0; mt < 2; ++mt) {
#pragma unroll
        for (int r = 0; r < 4; ++r) {
            const int node = row0 + mt * 16 + q * 4 + r;
            const bool ok = node < N_NODES;
            float sl = 0.f, sr = 0.f;
#pragma unroll
            for (int nt = 0; nt < 8; ++nt) {
                float v = acc[mt][nt][r];
                if (ok) hh[node * FOUT + nt * 16 + m] = (_Float16)v;
                sl = fmaf(v, al[nt], sl);
                sr = fmaf(v, ar[nt], sr);
            }
#pragma unroll
            for (int msk = 1; msk < 16; msk <<= 1) {
                sl += __shfl_xor(sl, msk, 64);
                sr += __shfl_xor(sr, msk, 64);
            }
            if (ok && m == 0) { score_l[node] = sl; score_r[node] = sr; }
        }
    }
}

// ---------------------------------------------------------------------------
// K2: partition edges into per-bucket SLABS (no global scan needed).
// Per-block space reserved with one atomicAdd per bucket.
// rec = (dst&255)<<17 | src
// ---------------------------------------------------------------------------
__global__ __launch_bounds__(512) void k_part(const int* __restrict__ ei,
                                              int* __restrict__ bcnt,
                                              unsigned* __restrict__ part)
{
    __shared__ unsigned staging[PCHUNK];
    __shared__ unsigned short bkt[PCHUNK];
    __shared__ int cnt[512];
    __shared__ int loc[512];
    __shared__ int gbase[NBUCKET];   // slab-local base for this block

    const int tid = threadIdx.x;
    const int e0  = blockIdx.x * PCHUNK;

    cnt[tid] = 0;
    __syncthreads();

    for (int i = tid; i < PCHUNK; i += 512)
        atomicAdd(&cnt[ei[e0 + i] >> 8], 1);
    __syncthreads();

    int v = cnt[tid];
    loc[tid] = v;
    __syncthreads();
    for (int off = 1; off < 512; off <<= 1) {
        int t = (tid >= off) ? loc[tid - off] : 0;
        __syncthreads();
        loc[tid] += t;
        __syncthreads();
    }
    int excl = loc[tid] - v;
    if (tid < NBUCKET && v > 0) gbase[tid] = atomicAdd(&bcnt[tid], v);
    loc[tid] = excl;
    cnt[tid] = excl;
    __syncthreads();

    for (int i = tid; i < PCHUNK; i += 512) {
        int dst = ei[e0 + i];
        int src = ei[N_EDGES + e0 + i];
        int b = dst >> 8;
        unsigned rec = ((unsigned)(dst & 255) << 17) | (unsigned)src;
        int p = atomicAdd(&cnt[b], 1);
        staging[p] = rec;
        bkt[p] = (unsigned short)b;
    }
    __syncthreads();

    for (int i = tid; i < PCHUNK; i += 512) {
        int b = bkt[i];
        int off = gbase[b] + (i - loc[b]);
        if (off < BCAP) part[b * BCAP + off] = staging[i];
    }
}

// ---------------------------------------------------------------------------
// K3: per-bucket counting sort by dstLow -> sorted src slab + rowbeg/rowend.
// ---------------------------------------------------------------------------
__global__ __launch_bounds__(512) void k_bucket(const unsigned* __restrict__ part,
                                                const int* __restrict__ bcnt,
                                                int* __restrict__ rowbeg,
                                                int* __restrict__ rowend,
                                                unsigned* __restrict__ csrs)
{
    __shared__ unsigned rin[BCAP];
    __shared__ unsigned rs[BCAP];
    __shared__ int hist[256];
    __shared__ int tmp[512];

    const int b   = blockIdx.x;
    const int tid = threadIdx.x;
    const int beg = b * BCAP;
    int cnt = bcnt[b];
    if (cnt > BCAP) cnt = BCAP;
    const int d0 = b << 8;

    if (tid < 256) hist[tid] = 0;
    __syncthreads();

    for (int i = tid; i < cnt; i += 512) {
        unsigned rec = part[beg + i];
        rin[i] = rec;
        atomicAdd(&hist[rec >> 17], 1);
    }
    __syncthreads();

    int v = (tid < 256) ? hist[tid] : 0;
    tmp[tid] = v;
    __syncthreads();
    for (int off = 1; off < 512; off <<= 1) {
        int t = (tid >= off) ? tmp[tid - off] : 0;
        __syncthreads();
        tmp[tid] += t;
        __syncthreads();
    }
    if (tid < 256) {
        int excl = tmp[tid] - v;
        hist[tid] = excl;          // cursor
        int d = d0 + tid;
        if (d < N_NODES) { rowbeg[d] = beg + excl; rowend[d] = beg + excl + v; }
    }
    __syncthreads();

    for (int i = tid; i < cnt; i += 512) {
        unsigned rec = rin[i];
        int p = atomicAdd(&hist[rec >> 17], 1);
        rs[p] = rec;
    }
    __syncthreads();

    for (int i = tid; i < cnt; i += 512)
        csrs[beg + i] = rs[i];
}

// ---------------------------------------------------------------------------
// K4: fused softmax-SpMM + bias + sigmoid-gate.
// One wave = one node; 4 edges/iter (one per 16-lane group). VALU-lean body:
//  - 2x-unrolled steady state with stage-local names (no rotation movs;
//    regalloc coalesces the loop-carried copies)
//  - validity hoisted out: iterations 0..nit-2 are provably in-bounds, only
//    the final iteration is masked
//  - fp16 h rows accumulated via v_fma_mix_f32 (fma(fpext(f16),f32,f32)),
//    1 inst/col instead of bf16's unpack+pk_fma (1.5 inst/col)
// csrs prefetched 2 stages ahead; score_r/hb gathers issued 1 stage ahead.
// ---------------------------------------------------------------------------
__global__ __launch_bounds__(256) void k_spmm_gate(
    const int* __restrict__ rowbeg, const int* __restrict__ rowend,
    const unsigned* __restrict__ csrs,
    const unsigned short* __restrict__ hb,
    const float* __restrict__ score_l, const float* __restrict__ score_r,
    const float* __restrict__ bias, const float* __restrict__ fc,
    const float* __restrict__ bf, float* __restrict__ out)
{
    const int lane = threadIdx.x & 63;
    const int g    = lane >> 4;                  // edge subgroup 0..3
    const int t    = lane & 15;                  // col group: t*8 .. t*8+7
    const int node = blockIdx.x * 4 + (threadIdx.x >> 6);
    if (node >= N_NODES) return;

    const int beg = rowbeg[node], end = rowend[node];
    const float sl = score_l[node];
    const unsigned short* __restrict__ hq = hb + (t << 3);

    float acc[8] = {0.f, 0.f, 0.f, 0.f, 0.f, 0.f, 0.f, 0.f};
    float denom = 0.f;

    if (end > beg) {
        const int nit  = (end - beg + 3) >> 2;   // wave-uniform
        const int nv   = nit - 1;                // leading always-valid iters
        const int last = end - 1;
        int j = beg + g;                         // index of current consume stage

        // prologue: recs for stages 0,1; gathers for stage 0
        unsigned rec1;
        float sr0; uint4 r0;
        {
            unsigned rec0 = csrs[min(j, last)];
            rec1 = csrs[min(j + 4, last)];
            int s0 = rec0 & 0x1FFFF;
            sr0 = score_r[s0];
            r0  = *(const uint4*)(hq + (s0 << 7));
        }

        int i = 0;
        for (; i + 2 <= nv; i += 2) {
            // stage A: prefetch rec(i+2); issue gathers(i+1); consume i
            unsigned rec2 = csrs[min(j + 8, last)];
            int s1 = rec1 & 0x1FFFF;
            float sr1 = score_r[s1];
            uint4 r1  = *(const uint4*)(hq + (s1 << 7));
            float w0 = edgew(sl, sr0);
            denom += w0;
            acc8(acc, r0, w0);
            j += 4;
            // stage B: prefetch rec(i+3); issue gathers(i+2); consume i+1
            unsigned rec3 = csrs[min(j + 8, last)];
            int s2 = rec2 & 0x1FFFF;
            float sr2 = score_r[s2];
            uint4 r2  = *(const uint4*)(hq + (s2 << 7));
            float w1 = edgew(sl, sr1);
            denom += w1;
            acc8(acc, r1, w1);
            j += 4;
            rec1 = rec3; sr0 = sr2; r0 = r2;     // coalesced by regalloc
        }
        if (i < nv) {
            // one more always-valid iteration (issues gathers for the final)
            int s1 = rec1 & 0x1FFFF;
            float sr1 = score_r[s1];
            uint4 r1  = *(const uint4*)(hq + (s1 << 7));
            float w0 = edgew(sl, sr0);
            denom += w0;
            acc8(acc, r0, w0);
            j += 4;
            sr0 = sr1; r0 = r1;
        }
        {
            // final iteration: mask lanes past end
            float w = (j < end) ? edgew(sl, sr0) : 0.f;
            denom += w;
            acc8(acc, r0, w);
        }
    }

    // fold the 4 groups' partials (lanes differ only in bits 4..5 per col slot)
#pragma unroll
    for (int k = 0; k < 8; ++k) {
        acc[k] += __shfl_xor(acc[k], 16, 64);
        acc[k] += __shfl_xor(acc[k], 32, 64);
    }
    denom += __shfl_xor(denom, 16, 64);
    denom += __shfl_xor(denom, 32, 64);

    const float inv = 1.0f / (denom + 1e-16f);

    float vx[8];
    float gp = 0.f;
#pragma unroll
    for (int i = 0; i < 8; ++i) {
        vx[i] = fmaf(acc[i], inv, bias[t * 8 + i]);
        gp = fmaf(vx[i], fc[t * 8 + i], gp);
    }
    // reduce gate partial across the 16 column lanes (bits 0..3)
#pragma unroll
    for (int msk = 1; msk < 16; msk <<= 1) gp += __shfl_xor(gp, msk, 64);
    const float gate = 1.0f / (1.0f + __expf(-(gp + bf[0])));

    float4 o;
    float* ov = &o.x;
    if (g == 0) {
#pragma unroll
        for (int i = 0; i < 4; ++i) {
            float v2 = vx[i];
            ov[i] = (v2 < 0.f ? 0.f : v2) + gate * (v2 > 0.f ? 0.f : v2);
        }
        *(float4*)&out[node * FOUT + t * 8] = o;
    } else if (g == 1) {
#pragma unroll
        for (int i = 0; i < 4; ++i) {
            float v2 = vx[4 + i];
            ov[i] = (v2 < 0.f ? 0.f : v2) + gate * (v2 > 0.f ? 0.f : v2);
        }
        *(float4*)&out[node * FOUT + t * 8 + 4] = o;
    }
}

// ---------------------------------------------------------------------------
extern "C" void kernel_launch(void* const* d_in, const int* in_sizes, int n_in,
                              void* d_out, int out_size, void* d_ws, size_t ws_size,
                              hipStream_t stream)
{
    const float* x      = (const float*)d_in[0];
    const int*   ei     = (const int*)d_in[1];
    const float* weight = (const float*)d_in[3];
    const float* bias   = (const float*)d_in[4];
    const float* a_l    = (const float*)d_in[5];
    const float* a_r    = (const float*)d_in[6];
    const float* fc     = (const float*)d_in[7];
    const float* bf     = (const float*)d_in[8];
    float* out = (float*)d_out;

    char* ws = (char*)d_ws;
    unsigned short* hb      = (unsigned short*)(ws);            // 25,600,000
    unsigned short* wt_sw   = (unsigned short*)(ws + 25600000); // 65,536
    float*          score_l = (float*)(ws + 25665536);          // 400,000
    float*          score_r = (float*)(ws + 26065536);          // 400,000
    int*            bcnt    = (int*)  (ws + 26465536);          // 2,048
    int*            rowbeg  = (int*)  (ws + 26467584);          // 400,000
    int*            rowend  = (int*)  (ws + 26867584);          // 400,000
    unsigned*       part    = (unsigned*)(ws + 27267584);       // 391*5120*4 = 8,007,680
    unsigned*       csrs    = (unsigned*)(ws + 35275264);       // 8,007,680
    // total ~43.3 MB

    k_wt<<<(FIN * FOUT + 255) / 256, 256, 0, stream>>>(weight, wt_sw, bcnt);

    k_gemm3<<<(N_NODES + 127) / 128, 256, 0, stream>>>(
        x, wt_sw, a_l, a_r, hb, score_l, score_r);

    k_part<<<PBLOCKS, 512, 0, stream>>>(ei, bcnt, part);
    k_bucket<<<NBUCKET, 512, 0, stream>>>(part, bcnt, rowbeg, rowend, csrs);

    k_spmm_gate<<<(N_NODES + 3) / 4, 256, 0, stream>>>(
        rowbeg, rowend, csrs, hb, score_l, score_r, bias, fc, bf, out);
}